// Round 1
// baseline (643.666 us; speedup 1.0000x reference)
//
#include <hip/hip_runtime.h>

typedef __attribute__((ext_vector_type(4))) float f32x4;
typedef __attribute__((ext_vector_type(8))) short bf16x8;

#define SCALE_ 0.17677669529663687f  // 32^-0.5
#define EPS_ 1e-5f

__device__ __forceinline__ unsigned short f2b(float f) {
  union { float f; unsigned int u; } c; c.f = f;
  unsigned int u = c.u;
  return (unsigned short)((u + 0x7FFFu + ((u >> 16) & 1u)) >> 16);
}

// K0: fp32 weights -> bf16, 4 matrices of 256x256, concatenated.
__global__ __launch_bounds__(256) void k0_cvt(const float* __restrict__ w0,
                                              const float* __restrict__ w1,
                                              const float* __restrict__ w2,
                                              const float* __restrict__ w3,
                                              unsigned short* __restrict__ dst) {
  int idx = blockIdx.x * 256 + threadIdx.x;  // 0..65535
  const float* s = (blockIdx.y == 0) ? w0 : (blockIdx.y == 1) ? w1 : (blockIdx.y == 2) ? w2 : w3;
  dst[blockIdx.y * 65536 + idx] = f2b(s[idx]);
}

// K1: LayerNorm + permutation gather + window partition -> Xg[w][l][c] bf16.
// One wave per token (shuffled coords b,n,t).
__global__ __launch_bounds__(256) void k1_ln(const float* __restrict__ x,
                                             const int* __restrict__ pn,
                                             const int* __restrict__ pt,
                                             const float* __restrict__ g,
                                             const float* __restrict__ be,
                                             unsigned short* __restrict__ Xg) {
  const int wave = threadIdx.x >> 6, lane = threadIdx.x & 63;
  const int tok = (blockIdx.x << 2) + wave;          // 0..131071
  const int b = tok >> 15, rem = tok & 32767;        // NB*T = 32768
  const int n = rem >> 9, t = rem & 511;             // T = 512
  const int spn = pn[(b << 6) + n];
  const int spt = pt[(b << 9) + t];
  const float* src = x + (((b << 6) + spn) * 512 + spt) * 256;
  float4 v = ((const float4*)src)[lane];
  float s = v.x + v.y + v.z + v.w;
  float ss = v.x * v.x + v.y * v.y + v.z * v.z + v.w * v.w;
  #pragma unroll
  for (int m = 1; m < 64; m <<= 1) {
    s += __shfl_xor(s, m);
    ss += __shfl_xor(ss, m);
  }
  const float mean = s * (1.0f / 256.0f);
  const float var = ss * (1.0f / 256.0f) - mean * mean;
  const float rs = rsqrtf(var + EPS_);
  float4 gg = ((const float4*)g)[lane];
  float4 bb = ((const float4*)be)[lane];
  const int w = ((b << 3) + (n >> 3)) * 64 + (t >> 3);
  const int l = ((n & 7) << 3) + (t & 7);
  ushort4 o;
  o.x = f2b((v.x - mean) * rs * gg.x + bb.x);
  o.y = f2b((v.y - mean) * rs * gg.y + bb.y);
  o.z = f2b((v.z - mean) * rs * gg.z + bb.z);
  o.w = f2b((v.w - mean) * rs * gg.w + bb.w);
  ((ushort4*)(Xg + ((w << 6) + l) * 256))[lane] = o;
}

// K2: per-window fused QKV + attention + projection + scatter-residual.
// Block = 256 threads = 4 waves; wave handles heads {2*wv, 2*wv+1}.
// Per-wave LDS scratch (ushorts): q[64][40] @0, k[64][40] @2560, vT[32][72] @5120
// (P[64][72] reuses q+k region). o_buf[64][264] overlays pool after barrier.
__global__ __launch_bounds__(256, 2) void k2_attn(
    const unsigned short* __restrict__ Xg, const unsigned short* __restrict__ Wall,
    const float* __restrict__ bq, const float* __restrict__ bk,
    const float* __restrict__ bv, const float* __restrict__ bp,
    const int* __restrict__ perm_n, const int* __restrict__ perm_t,
    const float* __restrict__ inpt, float* __restrict__ out) {
  __shared__ unsigned short pool[4 * 7424];
  __shared__ int tok_off[64];

  const int tid = threadIdx.x;
  const int wv = tid >> 6, lane = tid & 63, quad = lane >> 4, l15 = lane & 15;
  const int w = blockIdx.x;

  if (tid < 64) {
    const int l = tid;
    const int b = w >> 9, nbb = (w >> 6) & 7, tbb = w & 63;
    const int n = (nbb << 3) + (l >> 3), t = (tbb << 3) + (l & 7);
    const int spn = perm_n[(b << 6) + n], spt = perm_t[(b << 9) + t];
    tok_off[l] = (((b << 6) + spn) * 512 + spt) * 256;
  }
  __syncthreads();

  unsigned short* base = pool + wv * 7424;
  const unsigned short* Xw = Xg + w * (64 * 256);
  const f32x4 z4 = {0.f, 0.f, 0.f, 0.f};

  f32x4 oacc[2][4][2];

  for (int rep = 0; rep < 2; ++rep) {
    const int h = (wv << 1) + rep;

    // ---- QKV GEMMs for head h: acc[mat][mt][nt], M=64, N=32, K=256 ----
    f32x4 acc[3][4][2];
    #pragma unroll
    for (int mm = 0; mm < 3; ++mm)
      #pragma unroll
      for (int mt = 0; mt < 4; ++mt)
        #pragma unroll
        for (int nt = 0; nt < 2; ++nt) acc[mm][mt][nt] = z4;

    #pragma unroll
    for (int ks = 0; ks < 8; ++ks) {
      bf16x8 a[4];
      #pragma unroll
      for (int mt = 0; mt < 4; ++mt)
        a[mt] = *(const bf16x8*)(Xw + (mt * 16 + l15) * 256 + ks * 32 + quad * 8);
      #pragma unroll
      for (int mm = 0; mm < 3; ++mm) {
        #pragma unroll
        for (int nt = 0; nt < 2; ++nt) {
          bf16x8 bw = *(const bf16x8*)(Wall + mm * 65536 +
                                       (h * 32 + nt * 16 + l15) * 256 + ks * 32 + quad * 8);
          #pragma unroll
          for (int mt = 0; mt < 4; ++mt)
            acc[mm][mt][nt] =
                __builtin_amdgcn_mfma_f32_16x16x32_bf16(a[mt], bw, acc[mm][mt][nt], 0, 0, 0);
        }
      }
    }

    // ---- write q (scaled, +bias), k, vT to per-wave LDS ----
    #pragma unroll
    for (int nt = 0; nt < 2; ++nt) {
      const int ch = h * 32 + nt * 16 + l15;
      const float bqv = bq[ch], bkv = bk[ch], bvv = bv[ch];
      #pragma unroll
      for (int mt = 0; mt < 4; ++mt) {
        const int tok0 = mt * 16 + quad * 4;
        #pragma unroll
        for (int r = 0; r < 4; ++r) {
          base[(tok0 + r) * 40 + nt * 16 + l15] = f2b((acc[0][mt][nt][r] + bqv) * SCALE_);
          base[2560 + (tok0 + r) * 40 + nt * 16 + l15] = f2b(acc[1][mt][nt][r] + bkv);
          base[5120 + (nt * 16 + l15) * 72 + tok0 + r] = f2b(acc[2][mt][nt][r] + bvv);
        }
      }
    }

    // ---- S = q k^T (64x64, K=32) ----
    bf16x8 qa[4], kb[4];
    #pragma unroll
    for (int mt = 0; mt < 4; ++mt)
      qa[mt] = *(const bf16x8*)(base + (mt * 16 + l15) * 40 + quad * 8);
    #pragma unroll
    for (int nt = 0; nt < 4; ++nt)
      kb[nt] = *(const bf16x8*)(base + 2560 + (nt * 16 + l15) * 40 + quad * 8);
    f32x4 s[4][4];
    #pragma unroll
    for (int mt = 0; mt < 4; ++mt)
      #pragma unroll
      for (int nt = 0; nt < 4; ++nt)
        s[mt][nt] = __builtin_amdgcn_mfma_f32_16x16x32_bf16(qa[mt], kb[nt], z4, 0, 0, 0);

    // ---- softmax over rows (C-layout: col=lane&15, row=quad*4+r) ----
    #pragma unroll
    for (int mt = 0; mt < 4; ++mt) {
      #pragma unroll
      for (int r = 0; r < 4; ++r) {
        float mx = fmaxf(fmaxf(s[mt][0][r], s[mt][1][r]), fmaxf(s[mt][2][r], s[mt][3][r]));
        mx = fmaxf(mx, __shfl_xor(mx, 1));
        mx = fmaxf(mx, __shfl_xor(mx, 2));
        mx = fmaxf(mx, __shfl_xor(mx, 4));
        mx = fmaxf(mx, __shfl_xor(mx, 8));
        float e0 = __expf(s[mt][0][r] - mx);
        float e1 = __expf(s[mt][1][r] - mx);
        float e2 = __expf(s[mt][2][r] - mx);
        float e3 = __expf(s[mt][3][r] - mx);
        float sum = e0 + e1 + e2 + e3;
        sum += __shfl_xor(sum, 1);
        sum += __shfl_xor(sum, 2);
        sum += __shfl_xor(sum, 4);
        sum += __shfl_xor(sum, 8);
        const float inv = 1.0f / sum;
        s[mt][0][r] = e0 * inv;
        s[mt][1][r] = e1 * inv;
        s[mt][2][r] = e2 * inv;
        s[mt][3][r] = e3 * inv;
      }
    }

    // ---- P -> LDS (A-layout, reuses q+k region, stride 72) ----
    #pragma unroll
    for (int mt = 0; mt < 4; ++mt) {
      const int tok0 = mt * 16 + quad * 4;
      #pragma unroll
      for (int nt = 0; nt < 4; ++nt)
        #pragma unroll
        for (int r = 0; r < 4; ++r)
          base[(tok0 + r) * 72 + nt * 16 + l15] = f2b(s[mt][nt][r]);
    }

    // ---- O = P @ V  (M=64, N=32, K=64) ----
    #pragma unroll
    for (int mt = 0; mt < 4; ++mt)
      #pragma unroll
      for (int nd = 0; nd < 2; ++nd) oacc[rep][mt][nd] = z4;
    #pragma unroll
    for (int kc = 0; kc < 2; ++kc) {
      bf16x8 pa[4], vb[2];
      #pragma unroll
      for (int mt = 0; mt < 4; ++mt)
        pa[mt] = *(const bf16x8*)(base + (mt * 16 + l15) * 72 + kc * 32 + quad * 8);
      #pragma unroll
      for (int nd = 0; nd < 2; ++nd)
        vb[nd] = *(const bf16x8*)(base + 5120 + (nd * 16 + l15) * 72 + kc * 32 + quad * 8);
      #pragma unroll
      for (int mt = 0; mt < 4; ++mt)
        #pragma unroll
        for (int nd = 0; nd < 2; ++nd)
          oacc[rep][mt][nd] =
              __builtin_amdgcn_mfma_f32_16x16x32_bf16(pa[mt], vb[nd], oacc[rep][mt][nd], 0, 0, 0);
    }
  }

  // ---- gather all heads' O into o_buf (overlays per-wave pools) ----
  __syncthreads();
  unsigned short* obuf = pool;  // 64 x 264 ushorts
  #pragma unroll
  for (int rep = 0; rep < 2; ++rep) {
    const int h = (wv << 1) + rep;
    #pragma unroll
    for (int mt = 0; mt < 4; ++mt) {
      const int tok0 = mt * 16 + quad * 4;
      #pragma unroll
      for (int nd = 0; nd < 2; ++nd)
        #pragma unroll
        for (int r = 0; r < 4; ++r)
          obuf[(tok0 + r) * 264 + h * 32 + nd * 16 + l15] = f2b(oacc[rep][mt][nd][r]);
    }
  }
  __syncthreads();

  // ---- projection: wave wv computes output cols [wv*64, wv*64+64) ----
  f32x4 pacc[4][4];
  #pragma unroll
  for (int mt = 0; mt < 4; ++mt)
    #pragma unroll
    for (int nt = 0; nt < 4; ++nt) pacc[mt][nt] = z4;
  #pragma unroll
  for (int ks = 0; ks < 8; ++ks) {
    bf16x8 oa[4];
    #pragma unroll
    for (int mt = 0; mt < 4; ++mt)
      oa[mt] = *(const bf16x8*)(obuf + (mt * 16 + l15) * 264 + ks * 32 + quad * 8);
    #pragma unroll
    for (int nt = 0; nt < 4; ++nt) {
      bf16x8 wb = *(const bf16x8*)(Wall + 3 * 65536 +
                                   (wv * 64 + nt * 16 + l15) * 256 + ks * 32 + quad * 8);
      #pragma unroll
      for (int mt = 0; mt < 4; ++mt)
        pacc[mt][nt] = __builtin_amdgcn_mfma_f32_16x16x32_bf16(oa[mt], wb, pacc[mt][nt], 0, 0, 0);
    }
  }

  // ---- epilogue: +bp, scatter to unshuffled location, residual add ----
  #pragma unroll
  for (int nt = 0; nt < 4; ++nt) {
    const int ch = wv * 64 + nt * 16 + l15;
    const float bpv = bp[ch];
    #pragma unroll
    for (int mt = 0; mt < 4; ++mt) {
      #pragma unroll
      for (int r = 0; r < 4; ++r) {
        const int m = mt * 16 + quad * 4 + r;
        const int off = tok_off[m] + ch;
        out[off] = inpt[off] + pacc[mt][nt][r] + bpv;
      }
    }
  }
}

extern "C" void kernel_launch(void* const* d_in, const int* in_sizes, int n_in,
                              void* d_out, int out_size, void* d_ws, size_t ws_size,
                              hipStream_t stream) {
  const float* inpt = (const float*)d_in[0];
  const int* perm_n = (const int*)d_in[1];
  const int* perm_t = (const int*)d_in[2];
  const float* ln_g = (const float*)d_in[3];
  const float* ln_b = (const float*)d_in[4];
  const float* Wq = (const float*)d_in[5];
  const float* bq = (const float*)d_in[6];
  const float* Wk = (const float*)d_in[7];
  const float* bk = (const float*)d_in[8];
  const float* Wv = (const float*)d_in[9];
  const float* bv = (const float*)d_in[10];
  const float* Wp = (const float*)d_in[11];
  const float* bp = (const float*)d_in[12];
  float* out = (float*)d_out;

  // ws layout: Xg (2048*64*256 bf16 = 64 MiB) | Wall (4*65536 bf16 = 512 KiB)
  unsigned short* Xg = (unsigned short*)d_ws;
  unsigned short* Wall = (unsigned short*)((char*)d_ws + (size_t)67108864);

  k0_cvt<<<dim3(256, 4), 256, 0, stream>>>(Wq, Wk, Wv, Wp, Wall);
  k1_ln<<<32768, 256, 0, stream>>>(inpt, perm_n, perm_t, ln_g, ln_b, Xg);
  k2_attn<<<2048, 256, 0, stream>>>(Xg, Wall, bq, bk, bv, bp, perm_n, perm_t, inpt, out);
}